// Round 13
// baseline (185.457 us; speedup 1.0000x reference)
//
#include <hip/hip_runtime.h>
#include <hip/hip_bf16.h>

// DiffRenderer v12: v11b (nt stores, CONFIRMED -14us: L2 write-allocate was
// the 6-ablation-invariant throttle) + nontemporal LOGITS loads.
// Same mechanism, read side: 81MB streams through L2 once with zero reuse,
// allocating ~640K L2 lines that contend with the nt-store drain in TCC.
// Font loads stay cached (86KB, block-reused, L2-resident).
#define ROWS 384
#define COLS 768
#define NCH  69
#define CH   28
#define CW   14
#define KP   96             // K padded to 3 MFMA k-steps of 32
#define IMG_W 10752
#define ROW_U 104           // prob-row stride in ushorts (208B, 16B-aligned)

typedef __attribute__((ext_vector_type(8))) short bfrag;   // 8 bf16 (4 VGPR)
typedef __attribute__((ext_vector_type(4))) float f32x4;   // C/D frag / stores

__device__ __forceinline__ unsigned bf16bits(float x) {
    unsigned b = __float_as_uint(x);
    b += 0x7FFFu + ((b >> 16) & 1u);   // RTNE
    return b >> 16;
}

// ---- kernel 1: font (69,28,14) f32 -> Fh[28][16][96] bf16 ----
__global__ __launch_bounds__(256)
void font_prep(const float* __restrict__ font, unsigned short* __restrict__ Fh) {
    int idx = blockIdx.x * 256 + threadIdx.x;        // 28*16*96 = 43008
    if (idx >= CH * 16 * KP) return;
    int k  = idx % KP;
    int hw = idx / KP;
    int w  = hw % 16, h = hw / 16;
    float v = (w < CW && k < NCH) ? font[k * (CH * CW) + h * CW + w] : 0.f;
    Fh[idx] = (unsigned short)bf16bits(v);
}

// ---- kernel 2: softmax + MFMA blend + row-coalesced nt assemble ----
__global__ __launch_bounds__(128, 3)
void diffrender_v12(const float* __restrict__ logits,       // (294912,69) f32
                    const unsigned short* __restrict__ Fh,  // (28,16,96) bf16
                    float* __restrict__ out)                // (10752,10752) f32
{
    __shared__ __align__(16) unsigned short smem[2][64 * ROW_U]; // 26.6KB, per-wave

    const int tid  = threadIdx.x;
    const int lane = tid & 63;
    const int wv   = tid >> 6;
    const int cell = blockIdx.x * 128 + tid;         // row-major over (384,768)
    const int r    = blockIdx.x / 6;                 // cell row (6 blocks/row)
    const int cb   = (blockIdx.x % 6) * 128;         // first cell col of block

    // ---- per-thread softmax over 69 logits (nontemporal: zero reuse) ----
    const float* lp = logits + (size_t)cell * NCH;
    float e[NCH];
    float m = -INFINITY;
#pragma unroll
    for (int n = 0; n < NCH; ++n) { e[n] = __builtin_nontemporal_load(lp + n); m = fmaxf(m, e[n]); }
    float s = 0.f;
#pragma unroll
    for (int n = 0; n < NCH; ++n) { e[n] = __expf(e[n] - m); s += e[n]; }
    const float inv = 1.f / s;

    // ---- pack probs bf16 -> per-wave LDS row (k 0..95, zero-padded) ----
    unsigned* prow = (unsigned*)&smem[wv][(size_t)lane * ROW_U];
#pragma unroll
    for (int i = 0; i < 34; ++i)
        prow[i] = bf16bits(e[2 * i] * inv) | (bf16bits(e[2 * i + 1] * inv) << 16);
    prow[34] = bf16bits(e[68] * inv);
#pragma unroll
    for (int i = 35; i < 48; ++i) prow[i] = 0;

    // ---- this wave's 12 A-fragments (4 M-tiles x 3 k-steps) ----
    const int w15   = lane & 15;
    const int kgrp  = (lane >> 4) * 8;
    const int crow4 = (lane >> 4) * 4;
    bfrag a[4][3];
#pragma unroll
    for (int mt = 0; mt < 4; ++mt)
#pragma unroll
        for (int ks = 0; ks < 3; ++ks)
            a[mt][ks] = *(const bfrag*)&smem[wv][(size_t)(mt * 16 + w15) * ROW_U + ks * 32 + kgrp];

    // prob buffer dead after a-frag reads -> reuse as f32 stage (2 rows x 896)
    float* stage = (float*)&smem[wv][0];

    // ---- h loop: TWO image rows per iteration, double-buffered B ----
    const unsigned short* fb = Fh + (size_t)w15 * KP + kgrp;
    bfrag bcur[2][3], bnxt[2][3];
#pragma unroll
    for (int hh = 0; hh < 2; ++hh)
#pragma unroll
        for (int ks = 0; ks < 3; ++ks)
            bcur[hh][ks] = *(const bfrag*)(fb + (size_t)(hh * 16) * KP + ks * 32);

#pragma unroll 1
    for (int h2 = 0; h2 < CH / 2; ++h2) {
        const int h = 2 * h2;
        if (h2 + 1 < CH / 2) {
            const unsigned short* fn = fb + (size_t)((h + 2) * 16) * KP;
#pragma unroll
            for (int hh = 0; hh < 2; ++hh)
#pragma unroll
                for (int ks = 0; ks < 3; ++ks)
                    bnxt[hh][ks] = *(const bfrag*)(fn + (size_t)(hh * 16) * KP + ks * 32);
        }

        f32x4 acc[2][4];
#pragma unroll
        for (int hh = 0; hh < 2; ++hh)
#pragma unroll
            for (int mt = 0; mt < 4; ++mt)
                acc[hh][mt] = f32x4{0, 0, 0, 0};
#pragma unroll
        for (int hh = 0; hh < 2; ++hh)
#pragma unroll
            for (int mt = 0; mt < 4; ++mt)
#pragma unroll
                for (int ks = 0; ks < 3; ++ks)
                    acc[hh][mt] = __builtin_amdgcn_mfma_f32_16x16x32_bf16(
                        a[mt][ks], bcur[hh][ks], acc[hh][mt], 0, 0, 0);

        // transpose through per-wave LDS: stage[hh][cell_local*14 + w]
        if (w15 < CW) {
#pragma unroll
            for (int hh = 0; hh < 2; ++hh)
#pragma unroll
                for (int mt = 0; mt < 4; ++mt)
#pragma unroll
                    for (int j = 0; j < 4; ++j)
                        stage[hh * 896 + (mt * 16 + crow4 + j) * CW + w15] = acc[hh][mt][j];
        }

        // coalesced NONTEMPORAL stores: per row, 224 f32x4 (4 masked insts)
#pragma unroll
        for (int hh = 0; hh < 2; ++hh) {
            f32x4* o4 = (f32x4*)(out + (size_t)(r * CH + h + hh) * IMG_W
                                     + (size_t)(cb + wv * 64) * CW);
            const f32x4* s4 = (const f32x4*)(stage + hh * 896);
#pragma unroll
            for (int i = 0; i < 4; ++i) {
                const int idx = i * 64 + lane;
                if (idx < 224) __builtin_nontemporal_store(s4[idx], &o4[idx]);
            }
        }

#pragma unroll
        for (int hh = 0; hh < 2; ++hh)
#pragma unroll
            for (int ks = 0; ks < 3; ++ks)
                bcur[hh][ks] = bnxt[hh][ks];
    }
}

extern "C" void kernel_launch(void* const* d_in, const int* in_sizes, int n_in,
                              void* d_out, int out_size, void* d_ws, size_t ws_size,
                              hipStream_t stream) {
    const float* logits = (const float*)d_in[0];   // (384,768,69) f32
    const float* font   = (const float*)d_in[1];   // (69,28,14)  f32
    float* out          = (float*)d_out;           // (10752,10752) f32
    unsigned short* Fh  = (unsigned short*)d_ws;   // (28,16,96) bf16 = 86KB

    font_prep<<<(CH * 16 * KP + 255) / 256, 256, 0, stream>>>(font, Fh);

    const int blocks = (ROWS * COLS) / 128;        // 2304
    diffrender_v12<<<blocks, 128, 0, stream>>>(logits, Fh, out);
}

// Round 14
// 111.743 us; speedup vs baseline: 1.6597x; 1.6597x over previous
//
#include <hip/hip_runtime.h>
#include <hip/hip_bf16.h>

// DiffRenderer v13: v9 lean structure (17 waves/CU) + nt stores.
// Ledger: nt stores +14us (L2 write-allocate thrash confirmed). nt loads
// -78us (REVERTED: logits lines have heavy cross-lane spatial reuse in L1;
// nt bypass re-fetched each line dozens of times). Occupancy was null under
// the write-throttle regime (v9, 125us); re-test now that the throttle is
// lifted: 64-thr blocks, ROW_U=72 -> 9216B LDS -> 17 blocks/CU.
#define ROWS 384
#define COLS 768
#define NCH  69
#define CH   28
#define CW   14
#define KP   96             // font K padded to 3 k-steps of 32 (zeros past 68)
#define IMG_W 10752
#define ROW_U 72            // prob-row stride in ushorts (144B, 16B-aligned)

typedef __attribute__((ext_vector_type(8))) short bfrag;   // 8 bf16 (4 VGPR)
typedef __attribute__((ext_vector_type(4))) float f32x4;   // C/D frag / stores

__device__ __forceinline__ unsigned bf16bits(float x) {
    unsigned b = __float_as_uint(x);
    b += 0x7FFFu + ((b >> 16) & 1u);   // RTNE
    return b >> 16;
}

// ---- kernel 1: font (69,28,14) f32 -> Fh[28][16][96] bf16 (zero-padded) ----
__global__ __launch_bounds__(256)
void font_prep(const float* __restrict__ font, unsigned short* __restrict__ Fh) {
    int idx = blockIdx.x * 256 + threadIdx.x;        // 28*16*96 = 43008
    if (idx >= CH * 16 * KP) return;
    int k  = idx % KP;
    int hw = idx / KP;
    int w  = hw % 16, h = hw / 16;
    float v = (w < CW && k < NCH) ? font[k * (CH * CW) + h * CW + w] : 0.f;
    Fh[idx] = (unsigned short)bf16bits(v);
}

// ---- kernel 2: softmax + MFMA blend + row-coalesced nt-store assemble ----
__global__ __launch_bounds__(64, 4)
void diffrender_v13(const float* __restrict__ logits,       // (294912,69) f32
                    const unsigned short* __restrict__ Fh,  // (28,16,96) bf16
                    float* __restrict__ out)                // (10752,10752) f32
{
    __shared__ __align__(16) unsigned short Pa[64 * ROW_U]; // 9216 B

    const int lane = threadIdx.x;
    const int bid  = blockIdx.x;
    const int r    = bid / 12;                 // cell row (12 blocks/row)
    const int cb   = (bid % 12) * 64;          // first cell col of this block
    const int cell = bid * 64 + lane;

    // ---- per-thread softmax over 69 logits (cached loads: L1 cross-lane reuse) ----
    const float* lp = logits + (size_t)cell * NCH;
    float e[NCH];
    float m = -INFINITY;
#pragma unroll
    for (int n = 0; n < NCH; ++n) { e[n] = lp[n]; m = fmaxf(m, e[n]); }
    float s = 0.f;
#pragma unroll
    for (int n = 0; n < NCH; ++n) { e[n] = __expf(e[n] - m); s += e[n]; }
    const float inv = 1.f / s;

    // ---- pack probs bf16 -> LDS row `lane` (72 ushorts: k0..68 + 3 zeros) ----
    unsigned* prow = (unsigned*)&Pa[(size_t)lane * ROW_U];
#pragma unroll
    for (int i = 0; i < 34; ++i)
        prow[i] = bf16bits(e[2 * i] * inv) | (bf16bits(e[2 * i + 1] * inv) << 16);
    prow[34] = bf16bits(e[68] * inv);          // k68 | 0
    prow[35] = 0;                              // k70,71 = 0

    // ---- A-frags (probs): 4 M-tiles x 3 k-steps ----
    const int w15   = lane & 15;
    const int g     = lane >> 4;
    const int kgrp  = g * 8;
    const int crow4 = g * 4;
    bfrag a[4][3];
#pragma unroll
    for (int mt = 0; mt < 4; ++mt) {
        const size_t base = (size_t)(mt * 16 + w15) * ROW_U;
        a[mt][0] = *(const bfrag*)&Pa[base + kgrp];
        a[mt][1] = *(const bfrag*)&Pa[base + 32 + kgrp];
        // ks=2: all lane-groups read k64..71 (finite); font k>=69 is 0, and
        // for g>=1 the font slice k72..95 is all-zero -> product 0 regardless.
        a[mt][2] = *(const bfrag*)&Pa[base + 64];
    }

    // prob buffer dead after a-frag reads -> reuse as f32 stage (1 row x 896)
    float* stage = (float*)Pa;

    // ---- h loop: one image row per iter, double-buffered B (font) ----
    const unsigned short* fb = Fh + (size_t)w15 * KP + kgrp;
    bfrag bcur[3], bnxt[3];
#pragma unroll
    for (int ks = 0; ks < 3; ++ks)
        bcur[ks] = *(const bfrag*)(fb + ks * 32);

#pragma unroll 1
    for (int h = 0; h < CH; ++h) {
        if (h + 1 < CH) {
            const unsigned short* fn = fb + (size_t)(h + 1) * 16 * KP;
#pragma unroll
            for (int ks = 0; ks < 3; ++ks)
                bnxt[ks] = *(const bfrag*)(fn + ks * 32);
        }

        f32x4 acc[4] = {f32x4{0,0,0,0}, f32x4{0,0,0,0}, f32x4{0,0,0,0}, f32x4{0,0,0,0}};
#pragma unroll
        for (int mt = 0; mt < 4; ++mt)
#pragma unroll
            for (int ks = 0; ks < 3; ++ks)
                acc[mt] = __builtin_amdgcn_mfma_f32_16x16x32_bf16(a[mt][ks], bcur[ks], acc[mt], 0, 0, 0);

        // transpose through LDS: stage[cell_local*14 + w]
        if (w15 < CW) {
#pragma unroll
            for (int mt = 0; mt < 4; ++mt)
#pragma unroll
                for (int j = 0; j < 4; ++j)
                    stage[(mt * 16 + crow4 + j) * CW + w15] = acc[mt][j];
        }

        // coalesced NONTEMPORAL stores: 896 floats = 224 f32x4 (4 masked insts)
        f32x4* o4 = (f32x4*)(out + (size_t)(r * CH + h) * IMG_W + (size_t)cb * CW);
        const f32x4* s4 = (const f32x4*)stage;
#pragma unroll
        for (int i = 0; i < 4; ++i) {
            const int idx = i * 64 + lane;
            if (idx < 224) __builtin_nontemporal_store(s4[idx], &o4[idx]);
        }

#pragma unroll
        for (int ks = 0; ks < 3; ++ks) bcur[ks] = bnxt[ks];
    }
}

extern "C" void kernel_launch(void* const* d_in, const int* in_sizes, int n_in,
                              void* d_out, int out_size, void* d_ws, size_t ws_size,
                              hipStream_t stream) {
    const float* logits = (const float*)d_in[0];   // (294912,69) f32
    const float* font   = (const float*)d_in[1];   // (69,28,14)  f32
    float* out          = (float*)d_out;           // (10752,10752) f32
    unsigned short* Fh  = (unsigned short*)d_ws;   // (28,16,96) bf16 = 86KB

    font_prep<<<(CH * 16 * KP + 255) / 256, 256, 0, stream>>>(font, Fh);

    const int blocks = (ROWS * COLS) / 64;         // 4608 one-wave blocks
    diffrender_v13<<<blocks, 64, 0, stream>>>(logits, Fh, out);
}